// Round 2
// 431.603 us; speedup vs baseline: 1.0349x; 1.0349x over previous
//
#include <hip/hip_runtime.h>
#include <stdint.h>

typedef unsigned short u16;
typedef __attribute__((ext_vector_type(8))) short short8;    // 8 x bf16 (4 VGPRs)
typedef __attribute__((ext_vector_type(4))) float f32x4;     // 16x16 MFMA acc
typedef __attribute__((ext_vector_type(16))) float f32x16;   // 32x32 MFMA acc

#define MFMA16(a,b,c) __builtin_amdgcn_mfma_f32_16x16x32_bf16((a),(b),(c),0,0,0)
#define MFMA32(a,b,c) __builtin_amdgcn_mfma_f32_32x32x16_bf16((a),(b),(c),0,0,0)

__device__ __forceinline__ float fast_exp2(float x) {
  return __builtin_amdgcn_exp2f(x);   // v_exp_f32: D = 2^S0
}

__device__ __forceinline__ u16 f2bf(float f) {
  union { float f; uint32_t u; } v; v.f = f;
  uint32_t r = v.u + 0x7FFFu + ((v.u >> 16) & 1u);   // RNE
  return (u16)(r >> 16);
}
__device__ __forceinline__ float bf2f(uint32_t u) {
  union { uint32_t i; float f; } v; v.i = u << 16; return v.f;
}
// pack two f32 -> 2 x bf16 (RNE both halves; bit-exact with f2bf scalar path).
// NOTE: v_cvt_pk_bf16_f32 inline-asm was tried here (round 1) and produced a
// systematic ~0.2% bias vs RNE (absmax 1.2e-2 vs 2.4e-4) -> not RNE-compatible.
__device__ __forceinline__ uint32_t pack_bf16_rne(float lo, float hi) {
  return (uint32_t)f2bf(lo) | ((uint32_t)f2bf(hi) << 16);
}
// async global->LDS, 16B per lane; LDS dest = wave-uniform base + lane*16
__device__ __forceinline__ void async_copy16(void* lds, const void* g) {
  __builtin_amdgcn_global_load_lds(
      (const __attribute__((address_space(1))) uint32_t*)g,
      (__attribute__((address_space(3))) uint32_t*)lds, 16, 0, 0);
}

// in-register 8x8 u16 transpose across 8 lanes (lane8 = lane&7), 4 u32 regs
__device__ __forceinline__ void transpose8x8(uint32_t r[4], int lane8) {
  uint32_t a0, a1, a2, a3;
  a0 = __shfl_xor(r[0], 4); a1 = __shfl_xor(r[1], 4);
  a2 = __shfl_xor(r[2], 4); a3 = __shfl_xor(r[3], 4);
  if (lane8 & 4) { r[0] = a2; r[1] = a3; } else { r[2] = a0; r[3] = a1; }
  a0 = __shfl_xor(r[0], 2); a1 = __shfl_xor(r[1], 2);
  a2 = __shfl_xor(r[2], 2); a3 = __shfl_xor(r[3], 2);
  if (lane8 & 2) { r[0] = a1; r[2] = a3; } else { r[1] = a0; r[3] = a2; }
  a0 = __shfl_xor(r[0], 1); a1 = __shfl_xor(r[1], 1);
  a2 = __shfl_xor(r[2], 1); a3 = __shfl_xor(r[3], 1);
  uint32_t sel = (lane8 & 1) ? 0x03020706u : 0x05040100u;
  r[0] = __builtin_amdgcn_perm(a0, r[0], sel);
  r[1] = __builtin_amdgcn_perm(a1, r[1], sel);
  r[2] = __builtin_amdgcn_perm(a2, r[2], sel);
  r[3] = __builtin_amdgcn_perm(a3, r[3], sel);
}

// ---------------------------------------------------------------------------
// fused: Xbf = bf16(X);  mod = sigmoid(...)*0.125*log2e  (flash uses exp2)
__global__ __launch_bounds__(256) void castmod_kernel(
    const float* __restrict__ X, u16* __restrict__ Xbf,
    const float* __restrict__ cgW, const float* __restrict__ cgb,
    const float* __restrict__ cons, const float* __restrict__ amW,
    const float* __restrict__ amb, float* __restrict__ modp) {
  __shared__ float xs[1024];
  __shared__ float part[16][16];
  __shared__ float am[16];
  int row = blockIdx.x, t = threadIdx.x;
  {
    float4 v = ((const float4*)(X + (size_t)row * 1024))[t];
    xs[t * 4 + 0] = v.x; xs[t * 4 + 1] = v.y; xs[t * 4 + 2] = v.z; xs[t * 4 + 3] = v.w;
    uint2 o;
    o.x = (uint32_t)f2bf(v.x) | ((uint32_t)f2bf(v.y) << 16);
    o.y = (uint32_t)f2bf(v.z) | ((uint32_t)f2bf(v.w) << 16);
    ((uint2*)Xbf)[(size_t)row * 256 + t] = o;
  }
  if (t < 16) {
    float a = amb[t];
#pragma unroll
    for (int i = 0; i < 16; i++) a += cons[i] * amW[i * 16 + t];
    am[t] = a;
  }
  __syncthreads();
  int h = t & 15, ch = t >> 4;
  float p = 0.f;
#pragma unroll 8
  for (int k = ch * 64; k < ch * 64 + 64; k++) p += xs[k] * cgW[k * 16 + h];
  part[ch][h] = p;
  __syncthreads();
  if (t < 16) {
    float s = cgb[t] + am[t];
#pragma unroll
    for (int c = 0; c < 16; c++) s += part[c][t];
    int b = row >> 10, si = row & 1023;
    // 0.125 * log2(e) = 0.1803368801111...
    modp[((size_t)(b * 16 + t)) * 1024 + si] = 0.18033688f / (1.f + __expf(-s));
  }
}

// ---------------------------------------------------------------------------
// all weight prep in one kernel: 12 transpose+cast slices (z<12) + misc (z=12)
struct PrepArgs {
  const float* src[12];
  u16* dst[12];
  int sstride[12];
  const float* cabin; const float* bq; const float* bk; const float* bv;
  float* biasBig; float* lbuf;
};
__global__ __launch_bounds__(256) void prep_weights(PrepArgs p) {
  int z = blockIdx.z;
  int tx = threadIdx.x & 31, ty = threadIdx.x >> 5;   // (32,8) logical
  if (z < 12) {
    __shared__ float tile[32][33];
    const float* __restrict__ in = p.src[z];
    u16* __restrict__ out = p.dst[z];
    int sstr = p.sstride[z];
    int c0 = blockIdx.x * 32, r0 = blockIdx.y * 32;
#pragma unroll
    for (int j = 0; j < 4; j++)
      tile[ty + j * 8][tx] = in[(size_t)(r0 + ty + j * 8) * sstr + c0 + tx];
    __syncthreads();
#pragma unroll
    for (int j = 0; j < 4; j++)
      out[(size_t)(c0 + ty + j * 8) * 1024 + r0 + tx] = f2bf(tile[tx][ty + j * 8]);
  } else {
    int id = blockIdx.y * 32 + blockIdx.x, t = threadIdx.x;
    if (id < 24) {
      int i = id * 256 + t;   // 0..6143
      float v;
      if (i < 3072) v = p.cabin[i];
      else if (i < 4096) v = p.bq[i - 3072];
      else if (i < 5120) v = p.bk[i - 4096];
      else v = p.bv[i - 5120];
      p.biasBig[i] = v;
    } else if (id < 152) {
      p.lbuf[(id - 24) * 256 + t] = 0.f;
    }
  }
}

// ---------------------------------------------------------------------------
// bf16 GEMM, BK=64: C[M,N] = A[M,K] @ Bt[N,K]^T (+bias, optional blend)
template <int OUT_F32, int HAS_EXTRA, int BN>
__global__ __launch_bounds__(256, 3) void gemm_bt(
    const u16* __restrict__ A, const u16* __restrict__ Bt,
    const float* __restrict__ bias, const u16* __restrict__ extra,
    float alpha, float beta, void* __restrict__ Cout, int M, int N, int K) {
  constexpr int NJ = BN / 32;
  __shared__ u16 As[128 * 64];
  __shared__ u16 Bs[BN * 64];
  const int t = threadIdx.x;
  const int w = t >> 6, l = t & 63, lm = l & 15, lg = l >> 4;
  const int wm = w & 1, wn = w >> 1;
  const int m0 = blockIdx.y * 128, n0 = blockIdx.x * BN;
  const int rl = l >> 3, gsrc8 = ((l & 7) ^ (rl & 7)) * 8;
  const f32x4 fzero = {0.f, 0.f, 0.f, 0.f};
  f32x4 acc[4][NJ];
#pragma unroll
  for (int i = 0; i < 4; i++)
#pragma unroll
    for (int j = 0; j < NJ; j++) acc[i][j] = fzero;

  for (int kt = 0; kt < K; kt += 64) {
    __syncthreads();
#pragma unroll
    for (int c = 0; c < 4; c++) {
      int rb = c * 32 + w * 8;
      async_copy16(&As[rb * 64], A + (size_t)(m0 + rb + rl) * K + kt + gsrc8);
    }
#pragma unroll
    for (int c = 0; c < BN / 32; c++) {
      int rb = c * 32 + w * 8;
      async_copy16(&Bs[rb * 64], Bt + (size_t)(n0 + rb + rl) * K + kt + gsrc8);
    }
    __syncthreads();
#pragma unroll
    for (int kk = 0; kk < 2; kk++) {
      short8 af[4], bf[NJ];
      const int gph = ((kk * 4 + lg) ^ (lm & 7)) * 8;
#pragma unroll
      for (int i = 0; i < 4; i++)
        af[i] = *(const short8*)&As[(wm * 64 + i * 16 + lm) * 64 + gph];
#pragma unroll
      for (int j = 0; j < NJ; j++)
        bf[j] = *(const short8*)&Bs[(wn * (BN / 2) + j * 16 + lm) * 64 + gph];
#pragma unroll
      for (int i = 0; i < 4; i++)
#pragma unroll
        for (int j = 0; j < NJ; j++) acc[i][j] = MFMA16(af[i], bf[j], acc[i][j]);
    }
  }
#pragma unroll
  for (int i = 0; i < 4; i++) {
    int row0 = m0 + wm * 64 + i * 16 + lg * 4;
#pragma unroll
    for (int j = 0; j < NJ; j++) {
      int col = n0 + wn * (BN / 2) + j * 16 + lm;
      float bc = bias[col];
#pragma unroll
      for (int r = 0; r < 4; r++) {
        size_t idx = (size_t)(row0 + r) * N + col;
        float v = acc[i][j][r] + bc;
        if constexpr (HAS_EXTRA) v = alpha * v + beta * bf2f(extra[idx]);
        if constexpr (OUT_F32) ((float*)Cout)[idx] = v;
        else ((u16*)Cout)[idx] = f2bf(v);
      }
    }
  }
}

// ---------------------------------------------------------------------------
// mega in-projection: epilogue routes by column region (see round-4 notes)
__global__ __launch_bounds__(256, 3) void gemm_in3(
    const u16* __restrict__ A, const u16* __restrict__ BtBig,
    const float* __restrict__ bias, u16* __restrict__ qkOut,
    u16* __restrict__ Vtb, u16* __restrict__ qkvm) {
  constexpr int K = 1024;
  __shared__ u16 As[128 * 64];
  __shared__ u16 Bs[128 * 64];
  const int t = threadIdx.x;
  const int w = t >> 6, l = t & 63, lm = l & 15, lg = l >> 4;
  const int wm = w & 1, wn = w >> 1;
  const int m0 = blockIdx.y * 128, n0 = blockIdx.x * 128;
  const int rl = l >> 3, gsrc8 = ((l & 7) ^ (rl & 7)) * 8;
  const f32x4 fzero = {0.f, 0.f, 0.f, 0.f};
  f32x4 acc[4][4];
#pragma unroll
  for (int i = 0; i < 4; i++)
#pragma unroll
    for (int j = 0; j < 4; j++) acc[i][j] = fzero;

  for (int kt = 0; kt < K; kt += 64) {
    __syncthreads();
#pragma unroll
    for (int c = 0; c < 4; c++) {
      int rb = c * 32 + w * 8;
      async_copy16(&As[rb * 64], A + (size_t)(m0 + rb + rl) * K + kt + gsrc8);
      async_copy16(&Bs[rb * 64], BtBig + (size_t)(n0 + rb + rl) * K + kt + gsrc8);
    }
    __syncthreads();
#pragma unroll
    for (int kk = 0; kk < 2; kk++) {
      short8 af[4], bf[4];
      const int gph = ((kk * 4 + lg) ^ (lm & 7)) * 8;
#pragma unroll
      for (int i = 0; i < 4; i++)
        af[i] = *(const short8*)&As[(wm * 64 + i * 16 + lm) * 64 + gph];
#pragma unroll
      for (int j = 0; j < 4; j++)
        bf[j] = *(const short8*)&Bs[(wn * 64 + j * 16 + lm) * 64 + gph];
#pragma unroll
      for (int i = 0; i < 4; i++)
#pragma unroll
        for (int j = 0; j < 4; j++) acc[i][j] = MFMA16(af[i], bf[j], acc[i][j]);
    }
  }
#pragma unroll
  for (int i = 0; i < 4; i++) {
    int row0 = m0 + wm * 64 + i * 16 + lg * 4;
#pragma unroll
    for (int j = 0; j < 4; j++) {
      int col = n0 + wn * 64 + j * 16 + lm;
      float bc = bias[col];
      if (col < 2048) {
#pragma unroll
        for (int r = 0; r < 4; r++)
          qkOut[(size_t)(row0 + r) * 2048 + col] = f2bf(acc[i][j][r] + bc);
      } else if (col < 3072) {
        int b = row0 >> 10, q0 = row0 & 1023;
        int z = b * 4 + ((col - 2048) >> 8), d = (col - 2048) & 255;
        union { u16 pk[4]; uint2 v; } u;
#pragma unroll
        for (int r = 0; r < 4; r++) u.pk[r] = f2bf(acc[i][j][r] + bc);
        *(uint2*)&Vtb[((size_t)z * 256 + d) * 1024 + q0] = u.v;
      } else {
#pragma unroll
        for (int r = 0; r < 4; r++)
          qkvm[(size_t)(row0 + r) * 3072 + col - 3072] = f2bf(acc[i][j][r] + bc);
      }
    }
  }
}

// ---------------------------------------------------------------------------
// QK^T body with exp2 epilogue + fused row-sum atomics (fixed-max softmax).
// smem must provide 2 * 128*64 u16. scale2 = scale * log2(e).
__device__ __forceinline__ void qk_body(
    char* smem, const u16* __restrict__ qk, u16* __restrict__ P,
    float* __restrict__ lrow, float scale2, int nb, int mb, int z) {
  constexpr int QKS = 2048;
  u16* As = (u16*)smem;
  u16* Bs = (u16*)(smem + 128 * 64 * 2);
  const int t = threadIdx.x;
  const int w = t >> 6, l = t & 63, lm = l & 15, lg = l >> 4;
  const int wm = w & 1, wn = w >> 1;
  const int b = z >> 2, h = z & 3;
  const int m0 = mb * 128, n0 = nb * 128;
  const u16* Abase = qk + ((size_t)b << 10) * QKS + h * 256;          // Q
  const u16* Bbase = qk + ((size_t)b << 10) * QKS + 1024 + h * 256;   // K
  const int rl = l >> 3, gsrc8 = ((l & 7) ^ (rl & 7)) * 8;
  const f32x4 fzero = {0.f, 0.f, 0.f, 0.f};
  f32x4 acc[4][4];
#pragma unroll
  for (int i = 0; i < 4; i++)
#pragma unroll
    for (int j = 0; j < 4; j++) acc[i][j] = fzero;

#pragma unroll
  for (int kt = 0; kt < 256; kt += 64) {
    __syncthreads();
#pragma unroll
    for (int c = 0; c < 4; c++) {
      int rb = c * 32 + w * 8;
      async_copy16(&As[rb * 64], Abase + (size_t)(m0 + rb + rl) * QKS + kt + gsrc8);
      async_copy16(&Bs[rb * 64], Bbase + (size_t)(n0 + rb + rl) * QKS + kt + gsrc8);
    }
    __syncthreads();
#pragma unroll
    for (int kk = 0; kk < 2; kk++) {
      short8 af[4], bf[4];
      const int gph = ((kk * 4 + lg) ^ (lm & 7)) * 8;
#pragma unroll
      for (int i = 0; i < 4; i++)
        af[i] = *(const short8*)&As[(wm * 64 + i * 16 + lm) * 64 + gph];
#pragma unroll
      for (int j = 0; j < 4; j++)
        bf[j] = *(const short8*)&Bs[(wn * 64 + j * 16 + lm) * 64 + gph];
#pragma unroll
      for (int i = 0; i < 4; i++)
#pragma unroll
        for (int j = 0; j < 4; j++) acc[i][j] = MFMA16(af[i], bf[j], acc[i][j]);
    }
  }
  u16* Pz = P + ((size_t)z << 20);
#pragma unroll
  for (int i = 0; i < 4; i++) {
    int row0 = m0 + wm * 64 + i * 16 + lg * 4;
    float rsum[4] = {0.f, 0.f, 0.f, 0.f};
#pragma unroll
    for (int j = 0; j < 4; j++) {
      int col = n0 + wn * 64 + j * 16 + lm;
#pragma unroll
      for (int r = 0; r < 4; r++) {
        float p = fast_exp2(acc[i][j][r] * scale2);
        rsum[r] += p;
        Pz[(size_t)(row0 + r) * 1024 + col] = f2bf(p);
      }
    }
#pragma unroll
    for (int r = 0; r < 4; r++) {
      float s = rsum[r];
#pragma unroll
      for (int sh = 1; sh <= 8; sh <<= 1) s += __shfl_xor(s, sh);
      if (lm == 0) atomicAdd(&lrow[(z << 10) + row0 + r], s);
    }
  }
}

// standalone qk kernel (meta phase)
__global__ __launch_bounds__(256, 3) void gemm_qk_exp(
    const u16* __restrict__ qk, u16* __restrict__ P, float* __restrict__ lrow,
    float scale2) {
  __shared__ char smem[2 * 128 * 64 * 2];
  qk_body(smem, qk, P, lrow, scale2, blockIdx.x, blockIdx.y, blockIdx.z);
}

// ---------------------------------------------------------------------------
// flash body, 32x32x16 MFMA, register-resident P (swapped QK^T, T12 pattern).
// HD=64, NH=16, S=1024, BQ=128 (32 q-rows/wave), BKV=128, fixed-max exp2
// softmax. smem = 16384 (K) + 17408 (V^T) = 33792 B -> 4 blocks/CU.
//
// QK^T is computed SWAPPED: st = mfma(K_frag, Q_frag) -> S^T[kv][q=l31].
// The Q fragment loaded for the A-operand role is bit-identical as a
// B-operand, so the swap is free. Each lane then owns column q = qw+l31:
//   - mod scale rs and row-sum lsum are per-lane scalars (were 16 regs each)
//   - P^T packs to bf16 in-register (RNE f2bf pack; v_cvt_pk_bf16_f32 is NOT
//     RNE-compatible on this toolchain — round-1 failure); PV B-fragments are
//     rebuilt with one lane<->lane+32 exchange per word pair (shfl_xor 32).
// PV: O^T = mfma(V^T_frag, P^T_frag). ksteps 2n,2n+1 consume exactly the
// n-tile's 8 packed words, so only 8 pk words are ever live.
__device__ __forceinline__ void flash_body(
    char* smem, const u16* __restrict__ qkv, const float* __restrict__ modp,
    u16* __restrict__ outp, int fid) {
  constexpr int S = 1024, W3 = 3072, HD = 64, BKV = 128;
  constexpr int VSTR = 136;
  u16* Ks = (u16*)smem;                         // 128 x 64
  u16* Vt = (u16*)(smem + 16384);               // 64 x 136

  const int t = threadIdx.x, w = t >> 6, l = t & 63, l31 = l & 31, hl = l >> 5;
  const int rest = fid >> 3;
  const int q0 = (rest & 7) * 128;
  const int bh = (fid & 7) + 8 * (rest >> 3);    // 0..63, XCD-grouped
  const int b = bh >> 4, h = bh & 15;
  const size_t rowbase = (size_t)b * S;
  const int qw = q0 + w * 32;

  const int oc = t >> 3, kvo = t & 7;
  const int sd0 = (oc & 7) * 8;
  const int skvg = (oc >> 3) * 8;

  // Q fragments: lane holds Q[q=l31][hd = ks*16 + hl*8 + j]
  // (serves as B-operand Q^T[hd][q=l31] for the swapped QK^T)
  short8 qf[4];
  {
    const u16* qp = qkv + (rowbase + qw + l31) * W3 + h * HD + hl * 8;
#pragma unroll
    for (int ks = 0; ks < 4; ks++) qf[ks] = *(const short8*)(qp + ks * 16);
  }
  // per-lane row scale (modp pre-scaled by 0.125*log2e) and lazy row sum
  const float rs = modp[(size_t)bh * S + qw + l31];
  float lsum = 0.f;
  f32x16 oacc[2];          // O^T: [d-tile][reg]; col = q = l31
#pragma unroll
  for (int d = 0; d < 2; d++)
#pragma unroll
    for (int i = 0; i < 16; i++) oacc[d][i] = 0.f;

  for (int kb = 0; kb < S; kb += BKV) {
    __syncthreads();
    // ---- stage K: async DMA, XOR-granule swizzle on global side
#pragma unroll
    for (int c = 0; c < 4; c++) {
      int rb = c * 32 + w * 8;
      int row = rb + (l >> 3);
      int gsrc = ((l & 7) ^ (row & 7)) * 8;
      async_copy16(&Ks[rb * HD],
                   qkv + (rowbase + kb + row) * W3 + 1024 + h * HD + gsrc);
    }
    // ---- stage V transposed via in-register 8x8 butterfly
#pragma unroll
    for (int c = 0; c < 4; c++) {
      int kv = c * 32 + skvg + kvo;
      union { short8 s; uint32_t u[4]; } vv, vo;
      vv.s = *(const short8*)(qkv + (rowbase + kb + kv) * W3 + 2048 + h * HD + sd0);
      uint32_t r[4] = {vv.u[0], vv.u[1], vv.u[2], vv.u[3]};
      transpose8x8(r, kvo);
      vo.u[0] = r[0]; vo.u[1] = r[1]; vo.u[2] = r[2]; vo.u[3] = r[3];
      *(short8*)&Vt[(sd0 + kvo) * VSTR + c * 32 + skvg] = vo.s;
    }
    __syncthreads();

    // ---- per n-tile: S^T = K Q^T, exp2+pack, then PV ksteps 2n and 2n+1
#pragma unroll
    for (int n = 0; n < 4; n++) {
      f32x16 st;
#pragma unroll
      for (int i = 0; i < 16; i++) st[i] = 0.f;
      const int krow = n * 32 + l31;
#pragma unroll
      for (int ks = 0; ks < 4; ks++) {
        int g = ks * 2 + hl;
        short8 kf = *(const short8*)&Ks[krow * HD + ((g ^ (krow & 7)) * 8)];
        st = MFMA32(kf, qf[ks], st);            // SWAPPED: S^T[kv][q]
      }
      // p = exp2(s*mod'), lazy l, pack pairs: pk8[tt*2+s] holds
      // kv = n*32 + 8*tt + 2*s + 4*hl (elem0) and +1 (elem1), q = l31
      uint32_t pk8[8];
#pragma unroll
      for (int tt = 0; tt < 4; tt++) {
#pragma unroll
        for (int s = 0; s < 2; s++) {
          float p0 = fast_exp2(st[tt * 4 + 2 * s] * rs);
          float p1 = fast_exp2(st[tt * 4 + 2 * s + 1] * rs);
          lsum += p0 + p1;
          pk8[tt * 2 + s] = pack_bf16_rne(p0, p1);
        }
      }
      // PV: rebuild B-fragments P^T[kv = ks*16 + hl*8 + j][q = l31]
#pragma unroll
      for (int k2 = 0; k2 < 2; k2++) {
        const int ta = 2 * k2, tb = ta + 1;
        uint32_t pw[4];
#pragma unroll
        for (int s = 0; s < 2; s++) {
          uint32_t A = pk8[ta * 2 + s], B = pk8[tb * 2 + s];
          uint32_t Ax = __shfl_xor(A, 32), Bx = __shfl_xor(B, 32);
          pw[s] = hl ? Bx : A;        // word s   (kv = base + hl*8 + 2s)
          pw[2 + s] = hl ? B : Ax;    // word s+2 (kv = base + hl*8 + 2s+4)
        }
        union { uint32_t u[4]; short8 s8; } pt;
        pt.u[0] = pw[0]; pt.u[1] = pw[1]; pt.u[2] = pw[2]; pt.u[3] = pw[3];
        const int ks = 2 * n + k2;
#pragma unroll
        for (int dt = 0; dt < 2; dt++) {
          short8 vb = *(const short8*)&Vt[(dt * 32 + l31) * VSTR + ks * 16 + hl * 8];
          oacc[dt] = MFMA32(vb, pt.s8, oacc[dt]);   // O^T[d][q]
        }
      }
    }
  }
  // ---- l: each lane summed its hl-half of kv; partner lane has the rest
  float sfull = lsum + __shfl_xor(lsum, 32);
  const float invl = 1.f / sfull;
  // ---- store O^T: lane owns row q = qw + l31; regs 4tt..4tt+3 are
  // d = dt*32 + 8*tt + 4*hl + 0..3 (contiguous) -> 8B packed stores
#pragma unroll
  for (int dt = 0; dt < 2; dt++) {
#pragma unroll
    for (int tt = 0; tt < 4; tt++) {
      union { u16 pkv[4]; uint2 v; } u;
#pragma unroll
      for (int r = 0; r < 4; r++) u.pkv[r] = f2bf(oacc[dt][tt * 4 + r] * invl);
      *(uint2*)&outp[(rowbase + qw + l31) * 1024 + h * HD + dt * 32 + tt * 8 + hl * 4] = u.v;
    }
  }
}

// ---------------------------------------------------------------------------
// fused dispatch: 1536 blocks; every 3rd block runs the flash path (512),
// the rest run causal-QK exp GEMM (1024). Both consume gemm_in3's outputs,
// so they are independent and co-resident per CU (m114 co-scheduling).
// smem = 33792 B (flash needs 33792, qk needs 32768) -> 4 blocks/CU.
__global__ __launch_bounds__(256, 4) void fused_qk_flash(
    const u16* __restrict__ qkvm, const float* __restrict__ modp,
    u16* __restrict__ ctxm, const u16* __restrict__ caQK,
    u16* __restrict__ P, float* __restrict__ lrow, float scale2) {
  __shared__ char smem[33792];
  const int bid = blockIdx.x;
  const int q3 = bid / 3, m3 = bid - q3 * 3;
  if (m3 == 2) {
    flash_body(smem, qkvm, modp, ctxm, q3);
  } else {
    int qid = q3 * 2 + m3;                       // 0..1023
    qk_body(smem, caQK, P, lrow, scale2, qid & 7, (qid >> 3) & 7, qid >> 6);
  }
}

// ---------------------------------------------------------------------------
// batched PV: O[q][d] = (P[z] @ Vtb[z]^T) / l -> ctx[B*S][1024] at col h*256
__global__ __launch_bounds__(256, 3) void gemm_pv(
    const u16* __restrict__ P, const u16* __restrict__ Vtb,
    const float* __restrict__ lrow, u16* __restrict__ outp) {
  constexpr int K = 1024, BN = 64, NJ = 2;
  __shared__ u16 As[128 * 64];
  __shared__ u16 Bs[BN * 64];
  const int t = threadIdx.x;
  const int w = t >> 6, l = t & 63, lm = l & 15, lg = l >> 4;
  const int wm = w & 1, wn = w >> 1;
  const int z = blockIdx.z, b = z >> 2, h = z & 3;
  const int m0 = blockIdx.y * 128, n0 = blockIdx.x * BN;
  const u16* Abase = P + ((size_t)z << 20);
  const u16* Bbase = Vtb + ((size_t)z << 18);
  const int rl = l >> 3, gsrc8 = ((l & 7) ^ (rl & 7)) * 8;
  const f32x4 fzero = {0.f, 0.f, 0.f, 0.f};
  f32x4 acc[4][NJ];
#pragma unroll
  for (int i = 0; i < 4; i++)
#pragma unroll
    for (int j = 0; j < NJ; j++) acc[i][j] = fzero;

  for (int kt = 0; kt < K; kt += 64) {
    __syncthreads();
#pragma unroll
    for (int c = 0; c < 4; c++) {
      int rb = c * 32 + w * 8;
      async_copy16(&As[rb * 64], Abase + (size_t)(m0 + rb + rl) * K + kt + gsrc8);
    }
#pragma unroll
    for (int c = 0; c < BN / 32; c++) {
      int rb = c * 32 + w * 8;
      async_copy16(&Bs[rb * 64], Bbase + (size_t)(n0 + rb + rl) * K + kt + gsrc8);
    }
    __syncthreads();
#pragma unroll
    for (int kk = 0; kk < 2; kk++) {
      short8 af[4], bf[NJ];
      const int gph = ((kk * 4 + lg) ^ (lm & 7)) * 8;
#pragma unroll
      for (int i = 0; i < 4; i++)
        af[i] = *(const short8*)&As[(wm * 64 + i * 16 + lm) * 64 + gph];
#pragma unroll
      for (int j = 0; j < NJ; j++)
        bf[j] = *(const short8*)&Bs[(wn * (BN / 2) + j * 16 + lm) * 64 + gph];
#pragma unroll
      for (int i = 0; i < 4; i++)
#pragma unroll
        for (int j = 0; j < NJ; j++) acc[i][j] = MFMA16(af[i], bf[j], acc[i][j]);
    }
  }
#pragma unroll
  for (int i = 0; i < 4; i++) {
    int row0 = m0 + wm * 64 + i * 16 + lg * 4;
    float invl[4];
#pragma unroll
    for (int r = 0; r < 4; r++) invl[r] = 1.f / lrow[(z << 10) + row0 + r];
#pragma unroll
    for (int j = 0; j < NJ; j++) {
      int col = n0 + wn * (BN / 2) + j * 16 + lm;
#pragma unroll
      for (int r = 0; r < 4; r++)
        outp[(size_t)((b << 10) + row0 + r) * 1024 + h * 256 + col] =
            f2bf(acc[i][j][r] * invl[r]);
    }
  }
}

// ---------------------------------------------------------------------------
extern "C" void kernel_launch(void* const* d_in, const int* in_sizes, int n_in,
                              void* d_out, int out_size, void* d_ws, size_t ws_size,
                              hipStream_t stream) {
  (void)in_sizes; (void)n_in; (void)out_size; (void)ws_size;
  const float* X      = (const float*)d_in[0];
  const float* cons   = (const float*)d_in[1];
  const float* Wq     = (const float*)d_in[2];  const float* bq     = (const float*)d_in[3];
  const float* Wk     = (const float*)d_in[4];  const float* bk     = (const float*)d_in[5];
  const float* Wv     = (const float*)d_in[6];  const float* bv     = (const float*)d_in[7];
  const float* cgW    = (const float*)d_in[8];  const float* cgb    = (const float*)d_in[9];
  const float* amW    = (const float*)d_in[10]; const float* amb    = (const float*)d_in[11];
  const float* caWin  = (const float*)d_in[12]; const float* cabin  = (const float*)d_in[13];
  const float* caWout = (const float*)d_in[14]; const float* cabout = (const float*)d_in[15];
  const float* mcWin  = (const float*)d_in[16]; const float* mcbin  = (const float*)d_in[17];
  const float* mcWout = (const float*)d_in[18]; const float* mcbout = (const float*)d_in[19];
  const float* Wo     = (const float*)d_in[20]; const float* bo     = (const float*)d_in[21];

  char* ws = (char*)d_ws;
  size_t off = 0;
  auto alloc = [&](size_t bytes) -> void* {
    void* p = ws + off; off += (bytes + 255) & ~(size_t)255; return p;
  };
  u16*    Xbf     = (u16*)alloc((size_t)4096 * 1024 * 2);
  u16*    BtBig   = (u16*)alloc((size_t)6144 * 1024 * 2);        // caWin^T | Wqkv^T
  u16*    mcWinT  = (u16*)alloc((size_t)3072 * 1024 * 2);
  u16*    caWoutT = (u16*)alloc((size_t)1024 * 1024 * 2);
  u16*    mcWoutT = (u16*)alloc((size_t)1024 * 1024 * 2);
  u16*    WoT     = (u16*)alloc((size_t)1024 * 1024 * 2);
  float*  biasBig = (float*)alloc(6144 * 4);
  float*  modb    = (float*)alloc((size_t)64 * 1024 * 4);
  u16*    caQK    = (u16*)alloc((size_t)4096 * 2048 * 2);        // also mcQK
  u16*    qkvm    = (u16*)alloc((size_t)4096 * 3072 * 2);
  u16*    actx    = (u16*)alloc((size_t)4096 * 1024 * 2);
  u16*    ctxm    = (u16*)alloc((size_t)4096 * 1024 * 2);
  u16*    ctx1    = (u16*)alloc((size_t)4096 * 1024 * 2);
  u16*    Pbuf    = (u16*)alloc((size_t)16 * 1024 * 1024 * 2);   // 32 MB
  u16*    Vtb     = (u16*)alloc((size_t)16 * 256 * 1024 * 2);    // 8 MB
  float*  lbuf    = (float*)alloc((size_t)2 * 16384 * 4);        // l_ca | l_mc
  float*  l_ca    = lbuf;
  float*  l_mc    = lbuf + 16384;
  u16*    mcQK    = caQK;  // alias: caQK dead after fused qk
  u16*    mctx    = ctxm;  // alias: ctxm dead after blend1
  u16*    ctx2    = actx;  // alias: actx dead after blend1

  const float SC2 = 1.4426950408889634f / 16.f;   // log2(e)/16

  // ---- prep (2 launches)
  castmod_kernel<<<4096, 256, 0, stream>>>(X, Xbf, cgW, cgb, cons, amW, amb, modb);
  {
    PrepArgs pa;
    for (int s = 0; s < 3; s++) {
      pa.src[s] = caWin + s * 1024; pa.dst[s] = BtBig + (size_t)s * 1024 * 1024;
      pa.sstride[s] = 3072;
    }
    pa.src[3] = Wq; pa.dst[3] = BtBig + (size_t)3072 * 1024; pa.sstride[3] = 1024;
    pa.src[4] = Wk; pa.dst[4] = BtBig + (size_t)4096 * 1024; pa.sstride[4] = 1024;
    pa.src[5] = Wv; pa.dst[5] = BtBig + (size_t)5120 * 1024; pa.sstride[5] = 1024;
    for (int s = 0; s < 3; s++) {
      pa.src[6 + s] = mcWin + s * 1024; pa.dst[6 + s] = mcWinT + (size_t)s * 1024 * 1024;
      pa.sstride[6 + s] = 3072;
    }
    pa.src[9]  = caWout; pa.dst[9]  = caWoutT; pa.sstride[9]  = 1024;
    pa.src[10] = mcWout; pa.dst[10] = mcWoutT; pa.sstride[10] = 1024;
    pa.src[11] = Wo;     pa.dst[11] = WoT;     pa.sstride[11] = 1024;
    pa.cabin = cabin; pa.bq = bq; pa.bk = bk; pa.bv = bv;
    pa.biasBig = biasBig; pa.lbuf = lbuf;
    prep_weights<<<dim3(32, 32, 13), 256, 0, stream>>>(pa);
  }

  // ---- mega in-proj: causal QK + causal V^T + main QKV in one GEMM
  gemm_in3<<<dim3(48, 32), 256, 0, stream>>>(Xbf, BtBig, biasBig, caQK, Vtb, qkvm);
  // ---- fused: main flash attention + causal QK-exp GEMM (independent)
  fused_qk_flash<<<1536, 256, 0, stream>>>(qkvm, modb, ctxm, caQK, Pbuf, l_ca, SC2);
  // ---- causal PV
  gemm_pv<<<dim3(4, 8, 16), 256, 0, stream>>>(Pbuf, Vtb, l_ca, actx);
  // ctx1 = 0.3*ctxm + 0.7*(actx@caWout + cabout)
  gemm_bt<0, 1, 64><<<dim3(16, 32), 256, 0, stream>>>(actx, caWoutT, cabout, ctxm, 0.7f, 0.3f,
                                                      ctx1, 4096, 1024, 1024);
  // ---- meta branch
  gemm_in3<<<dim3(24, 32), 256, 0, stream>>>(ctx1, mcWinT, mcbin, mcQK, Vtb, qkvm /*unused*/);
  gemm_qk_exp<<<dim3(8, 8, 16), 256, 0, stream>>>(mcQK, Pbuf, l_mc, SC2);
  gemm_pv<<<dim3(4, 8, 16), 256, 0, stream>>>(Pbuf, Vtb, l_mc, mctx);
  // ctx2 = 0.85*ctx1 + 0.15*(mctx@mcWout + mcbout)
  gemm_bt<0, 1, 64><<<dim3(16, 32), 256, 0, stream>>>(mctx, mcWoutT, mcbout, ctx1, 0.15f, 0.85f,
                                                      ctx2, 4096, 1024, 1024);
  // out = ctx2@Wo + bo (fp32)
  gemm_bt<1, 0, 64><<<dim3(16, 32), 256, 0, stream>>>(ctx2, WoT, bo, nullptr, 0.f, 0.f,
                                                      d_out, 4096, 1024, 1024);
}

// Round 3
// 408.232 us; speedup vs baseline: 1.0942x; 1.0572x over previous
//
#include <hip/hip_runtime.h>
#include <stdint.h>

typedef unsigned short u16;
typedef __attribute__((ext_vector_type(8))) short short8;    // 8 x bf16 (4 VGPRs)
typedef __attribute__((ext_vector_type(4))) float f32x4;     // 16x16 MFMA acc
typedef __attribute__((ext_vector_type(16))) float f32x16;   // 32x32 MFMA acc

#define MFMA16(a,b,c) __builtin_amdgcn_mfma_f32_16x16x32_bf16((a),(b),(c),0,0,0)
#define MFMA32(a,b,c) __builtin_amdgcn_mfma_f32_32x32x16_bf16((a),(b),(c),0,0,0)

__device__ __forceinline__ float fast_exp2(float x) {
  return __builtin_amdgcn_exp2f(x);   // v_exp_f32: D = 2^S0
}

__device__ __forceinline__ u16 f2bf(float f) {
  union { float f; uint32_t u; } v; v.f = f;
  uint32_t r = v.u + 0x7FFFu + ((v.u >> 16) & 1u);   // RNE
  return (u16)(r >> 16);
}
__device__ __forceinline__ float bf2f(uint32_t u) {
  union { uint32_t i; float f; } v; v.i = u << 16; return v.f;
}
// pack two f32 -> 2 x bf16 (RNE both halves; bit-exact with f2bf scalar path).
// NOTE: v_cvt_pk_bf16_f32 inline-asm was tried here (round 1) and produced a
// systematic ~0.2% bias vs RNE (absmax 1.2e-2 vs 2.4e-4) -> not RNE-compatible.
__device__ __forceinline__ uint32_t pack_bf16_rne(float lo, float hi) {
  return (uint32_t)f2bf(lo) | ((uint32_t)f2bf(hi) << 16);
}
// async global->LDS, 16B per lane; LDS dest = wave-uniform base + lane*16
__device__ __forceinline__ void async_copy16(void* lds, const void* g) {
  __builtin_amdgcn_global_load_lds(
      (const __attribute__((address_space(1))) uint32_t*)g,
      (__attribute__((address_space(3))) uint32_t*)lds, 16, 0, 0);
}

// in-register 8x8 u16 transpose across 8 lanes (lane8 = lane&7), 4 u32 regs
__device__ __forceinline__ void transpose8x8(uint32_t r[4], int lane8) {
  uint32_t a0, a1, a2, a3;
  a0 = __shfl_xor(r[0], 4); a1 = __shfl_xor(r[1], 4);
  a2 = __shfl_xor(r[2], 4); a3 = __shfl_xor(r[3], 4);
  if (lane8 & 4) { r[0] = a2; r[1] = a3; } else { r[2] = a0; r[3] = a1; }
  a0 = __shfl_xor(r[0], 2); a1 = __shfl_xor(r[1], 2);
  a2 = __shfl_xor(r[2], 2); a3 = __shfl_xor(r[3], 2);
  if (lane8 & 2) { r[0] = a1; r[2] = a3; } else { r[1] = a0; r[3] = a2; }
  a0 = __shfl_xor(r[0], 1); a1 = __shfl_xor(r[1], 1);
  a2 = __shfl_xor(r[2], 1); a3 = __shfl_xor(r[3], 1);
  uint32_t sel = (lane8 & 1) ? 0x03020706u : 0x05040100u;
  r[0] = __builtin_amdgcn_perm(a0, r[0], sel);
  r[1] = __builtin_amdgcn_perm(a1, r[1], sel);
  r[2] = __builtin_amdgcn_perm(a2, r[2], sel);
  r[3] = __builtin_amdgcn_perm(a3, r[3], sel);
}

// ---------------------------------------------------------------------------
// fused: Xbf = bf16(X);  mod = sigmoid(...)*0.125*log2e  (flash uses exp2)
__global__ __launch_bounds__(256) void castmod_kernel(
    const float* __restrict__ X, u16* __restrict__ Xbf,
    const float* __restrict__ cgW, const float* __restrict__ cgb,
    const float* __restrict__ cons, const float* __restrict__ amW,
    const float* __restrict__ amb, float* __restrict__ modp) {
  __shared__ float xs[1024];
  __shared__ float part[16][16];
  __shared__ float am[16];
  int row = blockIdx.x, t = threadIdx.x;
  {
    float4 v = ((const float4*)(X + (size_t)row * 1024))[t];
    xs[t * 4 + 0] = v.x; xs[t * 4 + 1] = v.y; xs[t * 4 + 2] = v.z; xs[t * 4 + 3] = v.w;
    uint2 o;
    o.x = (uint32_t)f2bf(v.x) | ((uint32_t)f2bf(v.y) << 16);
    o.y = (uint32_t)f2bf(v.z) | ((uint32_t)f2bf(v.w) << 16);
    ((uint2*)Xbf)[(size_t)row * 256 + t] = o;
  }
  if (t < 16) {
    float a = amb[t];
#pragma unroll
    for (int i = 0; i < 16; i++) a += cons[i] * amW[i * 16 + t];
    am[t] = a;
  }
  __syncthreads();
  int h = t & 15, ch = t >> 4;
  float p = 0.f;
#pragma unroll 8
  for (int k = ch * 64; k < ch * 64 + 64; k++) p += xs[k] * cgW[k * 16 + h];
  part[ch][h] = p;
  __syncthreads();
  if (t < 16) {
    float s = cgb[t] + am[t];
#pragma unroll
    for (int c = 0; c < 16; c++) s += part[c][t];
    int b = row >> 10, si = row & 1023;
    // 0.125 * log2(e) = 0.1803368801111...
    modp[((size_t)(b * 16 + t)) * 1024 + si] = 0.18033688f / (1.f + __expf(-s));
  }
}

// ---------------------------------------------------------------------------
// all weight prep in one kernel: 12 transpose+cast slices (z<12) + misc (z=12)
struct PrepArgs {
  const float* src[12];
  u16* dst[12];
  int sstride[12];
  const float* cabin; const float* bq; const float* bk; const float* bv;
  float* biasBig; float* lbuf;
};
__global__ __launch_bounds__(256) void prep_weights(PrepArgs p) {
  int z = blockIdx.z;
  int tx = threadIdx.x & 31, ty = threadIdx.x >> 5;   // (32,8) logical
  if (z < 12) {
    __shared__ float tile[32][33];
    const float* __restrict__ in = p.src[z];
    u16* __restrict__ out = p.dst[z];
    int sstr = p.sstride[z];
    int c0 = blockIdx.x * 32, r0 = blockIdx.y * 32;
#pragma unroll
    for (int j = 0; j < 4; j++)
      tile[ty + j * 8][tx] = in[(size_t)(r0 + ty + j * 8) * sstr + c0 + tx];
    __syncthreads();
#pragma unroll
    for (int j = 0; j < 4; j++)
      out[(size_t)(c0 + ty + j * 8) * 1024 + r0 + tx] = f2bf(tile[tx][ty + j * 8]);
  } else {
    int id = blockIdx.y * 32 + blockIdx.x, t = threadIdx.x;
    if (id < 24) {
      int i = id * 256 + t;   // 0..6143
      float v;
      if (i < 3072) v = p.cabin[i];
      else if (i < 4096) v = p.bq[i - 3072];
      else if (i < 5120) v = p.bk[i - 4096];
      else v = p.bv[i - 5120];
      p.biasBig[i] = v;
    } else if (id < 152) {
      p.lbuf[(id - 24) * 256 + t] = 0.f;
    }
  }
}

// ---------------------------------------------------------------------------
// bf16 GEMM, BK=64: C[M,N] = A[M,K] @ Bt[N,K]^T (+bias, optional blend)
// (256,4): VGPR+AGPR fit the 128 cap (acc 32 AGPR + ~64 VGPR) -> 4 blocks/CU.
template <int OUT_F32, int HAS_EXTRA, int BN>
__global__ __launch_bounds__(256, 4) void gemm_bt(
    const u16* __restrict__ A, const u16* __restrict__ Bt,
    const float* __restrict__ bias, const u16* __restrict__ extra,
    float alpha, float beta, void* __restrict__ Cout, int M, int N, int K) {
  constexpr int NJ = BN / 32;
  __shared__ u16 As[128 * 64];
  __shared__ u16 Bs[BN * 64];
  const int t = threadIdx.x;
  const int w = t >> 6, l = t & 63, lm = l & 15, lg = l >> 4;
  const int wm = w & 1, wn = w >> 1;
  const int m0 = blockIdx.y * 128, n0 = blockIdx.x * BN;
  const int rl = l >> 3, gsrc8 = ((l & 7) ^ (rl & 7)) * 8;
  const f32x4 fzero = {0.f, 0.f, 0.f, 0.f};
  f32x4 acc[4][NJ];
#pragma unroll
  for (int i = 0; i < 4; i++)
#pragma unroll
    for (int j = 0; j < NJ; j++) acc[i][j] = fzero;

  for (int kt = 0; kt < K; kt += 64) {
    __syncthreads();
#pragma unroll
    for (int c = 0; c < 4; c++) {
      int rb = c * 32 + w * 8;
      async_copy16(&As[rb * 64], A + (size_t)(m0 + rb + rl) * K + kt + gsrc8);
    }
#pragma unroll
    for (int c = 0; c < BN / 32; c++) {
      int rb = c * 32 + w * 8;
      async_copy16(&Bs[rb * 64], Bt + (size_t)(n0 + rb + rl) * K + kt + gsrc8);
    }
    __syncthreads();
#pragma unroll
    for (int kk = 0; kk < 2; kk++) {
      short8 af[4], bf[NJ];
      const int gph = ((kk * 4 + lg) ^ (lm & 7)) * 8;
#pragma unroll
      for (int i = 0; i < 4; i++)
        af[i] = *(const short8*)&As[(wm * 64 + i * 16 + lm) * 64 + gph];
#pragma unroll
      for (int j = 0; j < NJ; j++)
        bf[j] = *(const short8*)&Bs[(wn * (BN / 2) + j * 16 + lm) * 64 + gph];
#pragma unroll
      for (int i = 0; i < 4; i++)
#pragma unroll
        for (int j = 0; j < NJ; j++) acc[i][j] = MFMA16(af[i], bf[j], acc[i][j]);
    }
  }
#pragma unroll
  for (int i = 0; i < 4; i++) {
    int row0 = m0 + wm * 64 + i * 16 + lg * 4;
#pragma unroll
    for (int j = 0; j < NJ; j++) {
      int col = n0 + wn * (BN / 2) + j * 16 + lm;
      float bc = bias[col];
#pragma unroll
      for (int r = 0; r < 4; r++) {
        size_t idx = (size_t)(row0 + r) * N + col;
        float v = acc[i][j][r] + bc;
        if constexpr (HAS_EXTRA) v = alpha * v + beta * bf2f(extra[idx]);
        if constexpr (OUT_F32) ((float*)Cout)[idx] = v;
        else ((u16*)Cout)[idx] = f2bf(v);
      }
    }
  }
}

// ---------------------------------------------------------------------------
// mega in-projection: epilogue routes by column region (see round-4 notes)
__global__ __launch_bounds__(256, 4) void gemm_in3(
    const u16* __restrict__ A, const u16* __restrict__ BtBig,
    const float* __restrict__ bias, u16* __restrict__ qkOut,
    u16* __restrict__ Vtb, u16* __restrict__ qkvm) {
  constexpr int K = 1024;
  __shared__ u16 As[128 * 64];
  __shared__ u16 Bs[128 * 64];
  const int t = threadIdx.x;
  const int w = t >> 6, l = t & 63, lm = l & 15, lg = l >> 4;
  const int wm = w & 1, wn = w >> 1;
  const int m0 = blockIdx.y * 128, n0 = blockIdx.x * 128;
  const int rl = l >> 3, gsrc8 = ((l & 7) ^ (rl & 7)) * 8;
  const f32x4 fzero = {0.f, 0.f, 0.f, 0.f};
  f32x4 acc[4][4];
#pragma unroll
  for (int i = 0; i < 4; i++)
#pragma unroll
    for (int j = 0; j < 4; j++) acc[i][j] = fzero;

  for (int kt = 0; kt < K; kt += 64) {
    __syncthreads();
#pragma unroll
    for (int c = 0; c < 4; c++) {
      int rb = c * 32 + w * 8;
      async_copy16(&As[rb * 64], A + (size_t)(m0 + rb + rl) * K + kt + gsrc8);
      async_copy16(&Bs[rb * 64], BtBig + (size_t)(n0 + rb + rl) * K + kt + gsrc8);
    }
    __syncthreads();
#pragma unroll
    for (int kk = 0; kk < 2; kk++) {
      short8 af[4], bf[4];
      const int gph = ((kk * 4 + lg) ^ (lm & 7)) * 8;
#pragma unroll
      for (int i = 0; i < 4; i++)
        af[i] = *(const short8*)&As[(wm * 64 + i * 16 + lm) * 64 + gph];
#pragma unroll
      for (int j = 0; j < 4; j++)
        bf[j] = *(const short8*)&Bs[(wn * 64 + j * 16 + lm) * 64 + gph];
#pragma unroll
      for (int i = 0; i < 4; i++)
#pragma unroll
        for (int j = 0; j < 4; j++) acc[i][j] = MFMA16(af[i], bf[j], acc[i][j]);
    }
  }
#pragma unroll
  for (int i = 0; i < 4; i++) {
    int row0 = m0 + wm * 64 + i * 16 + lg * 4;
#pragma unroll
    for (int j = 0; j < 4; j++) {
      int col = n0 + wn * 64 + j * 16 + lm;
      float bc = bias[col];
      if (col < 2048) {
#pragma unroll
        for (int r = 0; r < 4; r++)
          qkOut[(size_t)(row0 + r) * 2048 + col] = f2bf(acc[i][j][r] + bc);
      } else if (col < 3072) {
        int b = row0 >> 10, q0 = row0 & 1023;
        int z = b * 4 + ((col - 2048) >> 8), d = (col - 2048) & 255;
        union { u16 pk[4]; uint2 v; } u;
#pragma unroll
        for (int r = 0; r < 4; r++) u.pk[r] = f2bf(acc[i][j][r] + bc);
        *(uint2*)&Vtb[((size_t)z * 256 + d) * 1024 + q0] = u.v;
      } else {
#pragma unroll
        for (int r = 0; r < 4; r++)
          qkvm[(size_t)(row0 + r) * 3072 + col - 3072] = f2bf(acc[i][j][r] + bc);
      }
    }
  }
}

// ---------------------------------------------------------------------------
// QK^T body with exp2 epilogue + fused row-sum atomics (fixed-max softmax).
// smem must provide 2 * 128*64 u16. scale2 = scale * log2(e).
__device__ __forceinline__ void qk_body(
    char* smem, const u16* __restrict__ qk, u16* __restrict__ P,
    float* __restrict__ lrow, float scale2, int nb, int mb, int z) {
  constexpr int QKS = 2048;
  u16* As = (u16*)smem;
  u16* Bs = (u16*)(smem + 128 * 64 * 2);
  const int t = threadIdx.x;
  const int w = t >> 6, l = t & 63, lm = l & 15, lg = l >> 4;
  const int wm = w & 1, wn = w >> 1;
  const int b = z >> 2, h = z & 3;
  const int m0 = mb * 128, n0 = nb * 128;
  const u16* Abase = qk + ((size_t)b << 10) * QKS + h * 256;          // Q
  const u16* Bbase = qk + ((size_t)b << 10) * QKS + 1024 + h * 256;   // K
  const int rl = l >> 3, gsrc8 = ((l & 7) ^ (rl & 7)) * 8;
  const f32x4 fzero = {0.f, 0.f, 0.f, 0.f};
  f32x4 acc[4][4];
#pragma unroll
  for (int i = 0; i < 4; i++)
#pragma unroll
    for (int j = 0; j < 4; j++) acc[i][j] = fzero;

#pragma unroll
  for (int kt = 0; kt < 256; kt += 64) {
    __syncthreads();
#pragma unroll
    for (int c = 0; c < 4; c++) {
      int rb = c * 32 + w * 8;
      async_copy16(&As[rb * 64], Abase + (size_t)(m0 + rb + rl) * QKS + kt + gsrc8);
      async_copy16(&Bs[rb * 64], Bbase + (size_t)(n0 + rb + rl) * QKS + kt + gsrc8);
    }
    __syncthreads();
#pragma unroll
    for (int kk = 0; kk < 2; kk++) {
      short8 af[4], bf[4];
      const int gph = ((kk * 4 + lg) ^ (lm & 7)) * 8;
#pragma unroll
      for (int i = 0; i < 4; i++)
        af[i] = *(const short8*)&As[(wm * 64 + i * 16 + lm) * 64 + gph];
#pragma unroll
      for (int j = 0; j < 4; j++)
        bf[j] = *(const short8*)&Bs[(wn * 64 + j * 16 + lm) * 64 + gph];
#pragma unroll
      for (int i = 0; i < 4; i++)
#pragma unroll
        for (int j = 0; j < 4; j++) acc[i][j] = MFMA16(af[i], bf[j], acc[i][j]);
    }
  }
  u16* Pz = P + ((size_t)z << 20);
#pragma unroll
  for (int i = 0; i < 4; i++) {
    int row0 = m0 + wm * 64 + i * 16 + lg * 4;
    float rsum[4] = {0.f, 0.f, 0.f, 0.f};
#pragma unroll
    for (int j = 0; j < 4; j++) {
      int col = n0 + wn * 64 + j * 16 + lm;
#pragma unroll
      for (int r = 0; r < 4; r++) {
        float p = fast_exp2(acc[i][j][r] * scale2);
        rsum[r] += p;
        Pz[(size_t)(row0 + r) * 1024 + col] = f2bf(p);
      }
    }
#pragma unroll
    for (int r = 0; r < 4; r++) {
      float s = rsum[r];
#pragma unroll
      for (int sh = 1; sh <= 8; sh <<= 1) s += __shfl_xor(s, sh);
      if (lm == 0) atomicAdd(&lrow[(z << 10) + row0 + r], s);
    }
  }
}

// standalone qk kernel (meta phase); 32 KB smem -> 4 blocks/CU at (256,4)
__global__ __launch_bounds__(256, 4) void gemm_qk_exp(
    const u16* __restrict__ qk, u16* __restrict__ P, float* __restrict__ lrow,
    float scale2) {
  __shared__ char smem[2 * 128 * 64 * 2];
  qk_body(smem, qk, P, lrow, scale2, blockIdx.x, blockIdx.y, blockIdx.z);
}

// ---------------------------------------------------------------------------
// flash body, 32x32x16 MFMA, register-resident P (swapped QK^T, T12 pattern).
// HD=64, NH=16, S=1024, BQ=128 (32 q-rows/wave), BKV=128, fixed-max exp2
// softmax. smem = 16384 (K) + 17408 (V^T) = 33792 B -> 4 blocks/CU.
//
// QK^T is computed SWAPPED: st = mfma(K_frag, Q_frag) -> S^T[kv][q=l31].
// The Q fragment loaded for the A-operand role is bit-identical as a
// B-operand, so the swap is free. Each lane then owns column q = qw+l31:
//   - mod scale rs and row-sum lsum are per-lane scalars (were 16 regs each)
//   - P^T packs to bf16 in-register (RNE f2bf pack; v_cvt_pk_bf16_f32 is NOT
//     RNE-compatible on this toolchain — round-1 failure); PV B-fragments are
//     rebuilt with one lane<->lane+32 exchange per word pair (shfl_xor 32).
// PV: O^T = mfma(V^T_frag, P^T_frag). ksteps 2n,2n+1 consume exactly the
// n-tile's 8 packed words, so only 8 pk words are ever live.
__device__ __forceinline__ void flash_body(
    char* smem, const u16* __restrict__ qkv, const float* __restrict__ modp,
    u16* __restrict__ outp, int fid) {
  constexpr int S = 1024, W3 = 3072, HD = 64, BKV = 128;
  constexpr int VSTR = 136;
  u16* Ks = (u16*)smem;                         // 128 x 64
  u16* Vt = (u16*)(smem + 16384);               // 64 x 136

  const int t = threadIdx.x, w = t >> 6, l = t & 63, l31 = l & 31, hl = l >> 5;
  const int rest = fid >> 3;
  const int q0 = (rest & 7) * 128;
  const int bh = (fid & 7) + 8 * (rest >> 3);    // 0..63, XCD-grouped
  const int b = bh >> 4, h = bh & 15;
  const size_t rowbase = (size_t)b * S;
  const int qw = q0 + w * 32;

  const int oc = t >> 3, kvo = t & 7;
  const int sd0 = (oc & 7) * 8;
  const int skvg = (oc >> 3) * 8;

  // Q fragments: lane holds Q[q=l31][hd = ks*16 + hl*8 + j]
  // (serves as B-operand Q^T[hd][q=l31] for the swapped QK^T)
  short8 qf[4];
  {
    const u16* qp = qkv + (rowbase + qw + l31) * W3 + h * HD + hl * 8;
#pragma unroll
    for (int ks = 0; ks < 4; ks++) qf[ks] = *(const short8*)(qp + ks * 16);
  }
  // per-lane row scale (modp pre-scaled by 0.125*log2e) and lazy row sum
  const float rs = modp[(size_t)bh * S + qw + l31];
  float lsum = 0.f;
  f32x16 oacc[2];          // O^T: [d-tile][reg]; col = q = l31
#pragma unroll
  for (int d = 0; d < 2; d++)
#pragma unroll
    for (int i = 0; i < 16; i++) oacc[d][i] = 0.f;

  for (int kb = 0; kb < S; kb += BKV) {
    __syncthreads();
    // ---- stage K: async DMA, XOR-granule swizzle on global side
#pragma unroll
    for (int c = 0; c < 4; c++) {
      int rb = c * 32 + w * 8;
      int row = rb + (l >> 3);
      int gsrc = ((l & 7) ^ (row & 7)) * 8;
      async_copy16(&Ks[rb * HD],
                   qkv + (rowbase + kb + row) * W3 + 1024 + h * HD + gsrc);
    }
    // ---- stage V transposed via in-register 8x8 butterfly
#pragma unroll
    for (int c = 0; c < 4; c++) {
      int kv = c * 32 + skvg + kvo;
      union { short8 s; uint32_t u[4]; } vv, vo;
      vv.s = *(const short8*)(qkv + (rowbase + kb + kv) * W3 + 2048 + h * HD + sd0);
      uint32_t r[4] = {vv.u[0], vv.u[1], vv.u[2], vv.u[3]};
      transpose8x8(r, kvo);
      vo.u[0] = r[0]; vo.u[1] = r[1]; vo.u[2] = r[2]; vo.u[3] = r[3];
      *(short8*)&Vt[(sd0 + kvo) * VSTR + c * 32 + skvg] = vo.s;
    }
    __syncthreads();

    // ---- per n-tile: S^T = K Q^T, exp2+pack, then PV ksteps 2n and 2n+1
#pragma unroll
    for (int n = 0; n < 4; n++) {
      f32x16 st;
#pragma unroll
      for (int i = 0; i < 16; i++) st[i] = 0.f;
      const int krow = n * 32 + l31;
#pragma unroll
      for (int ks = 0; ks < 4; ks++) {
        int g = ks * 2 + hl;
        short8 kf = *(const short8*)&Ks[krow * HD + ((g ^ (krow & 7)) * 8)];
        st = MFMA32(kf, qf[ks], st);            // SWAPPED: S^T[kv][q]
      }
      // p = exp2(s*mod'), lazy l, pack pairs: pk8[tt*2+s] holds
      // kv = n*32 + 8*tt + 2*s + 4*hl (elem0) and +1 (elem1), q = l31
      uint32_t pk8[8];
#pragma unroll
      for (int tt = 0; tt < 4; tt++) {
#pragma unroll
        for (int s = 0; s < 2; s++) {
          float p0 = fast_exp2(st[tt * 4 + 2 * s] * rs);
          float p1 = fast_exp2(st[tt * 4 + 2 * s + 1] * rs);
          lsum += p0 + p1;
          pk8[tt * 2 + s] = pack_bf16_rne(p0, p1);
        }
      }
      // PV: rebuild B-fragments P^T[kv = ks*16 + hl*8 + j][q = l31]
#pragma unroll
      for (int k2 = 0; k2 < 2; k2++) {
        const int ta = 2 * k2, tb = ta + 1;
        uint32_t pw[4];
#pragma unroll
        for (int s = 0; s < 2; s++) {
          uint32_t A = pk8[ta * 2 + s], B = pk8[tb * 2 + s];
          uint32_t Ax = __shfl_xor(A, 32), Bx = __shfl_xor(B, 32);
          pw[s] = hl ? Bx : A;        // word s   (kv = base + hl*8 + 2s)
          pw[2 + s] = hl ? B : Ax;    // word s+2 (kv = base + hl*8 + 2s+4)
        }
        union { uint32_t u[4]; short8 s8; } pt;
        pt.u[0] = pw[0]; pt.u[1] = pw[1]; pt.u[2] = pw[2]; pt.u[3] = pw[3];
        const int ks = 2 * n + k2;
#pragma unroll
        for (int dt = 0; dt < 2; dt++) {
          short8 vb = *(const short8*)&Vt[(dt * 32 + l31) * VSTR + ks * 16 + hl * 8];
          oacc[dt] = MFMA32(vb, pt.s8, oacc[dt]);   // O^T[d][q]
        }
      }
    }
  }
  // ---- l: each lane summed its hl-half of kv; partner lane has the rest
  float sfull = lsum + __shfl_xor(lsum, 32);
  const float invl = 1.f / sfull;
  // ---- store O^T: lane owns row q = qw + l31; regs 4tt..4tt+3 are
  // d = dt*32 + 8*tt + 4*hl + 0..3 (contiguous) -> 8B packed stores
#pragma unroll
  for (int dt = 0; dt < 2; dt++) {
#pragma unroll
    for (int tt = 0; tt < 4; tt++) {
      union { u16 pkv[4]; uint2 v; } u;
#pragma unroll
      for (int r = 0; r < 4; r++) u.pkv[r] = f2bf(oacc[dt][tt * 4 + r] * invl);
      *(uint2*)&outp[(rowbase + qw + l31) * 1024 + h * HD + dt * 32 + tt * 8 + hl * 4] = u.v;
    }
  }
}

// ---------------------------------------------------------------------------
// fused dispatch: 1536 blocks. The 512 LONG flash blocks go FIRST (LPT load
// balancing; also fid&7 == blockIdx&7 aligns with the XCD round-robin), the
// 1024 short causal-QK exp GEMM blocks fill in behind and form the tail.
// Both consume gemm_in3's outputs, so they are independent and co-resident
// per CU (m114 co-scheduling). smem = 33792 B -> 4 blocks/CU.
__global__ __launch_bounds__(256, 4) void fused_qk_flash(
    const u16* __restrict__ qkvm, const float* __restrict__ modp,
    u16* __restrict__ ctxm, const u16* __restrict__ caQK,
    u16* __restrict__ P, float* __restrict__ lrow, float scale2) {
  __shared__ char smem[33792];
  const int bid = blockIdx.x;
  if (bid < 512) {
    flash_body(smem, qkvm, modp, ctxm, bid);
  } else {
    int qid = bid - 512;                         // 0..1023
    qk_body(smem, caQK, P, lrow, scale2, qid & 7, (qid >> 3) & 7, qid >> 6);
  }
}

// ---------------------------------------------------------------------------
// batched PV: O[q][d] = (P[z] @ Vtb[z]^T) / l -> ctx[B*S][1024] at col h*256
__global__ __launch_bounds__(256, 4) void gemm_pv(
    const u16* __restrict__ P, const u16* __restrict__ Vtb,
    const float* __restrict__ lrow, u16* __restrict__ outp) {
  constexpr int K = 1024, BN = 64, NJ = 2;
  __shared__ u16 As[128 * 64];
  __shared__ u16 Bs[BN * 64];
  const int t = threadIdx.x;
  const int w = t >> 6, l = t & 63, lm = l & 15, lg = l >> 4;
  const int wm = w & 1, wn = w >> 1;
  const int z = blockIdx.z, b = z >> 2, h = z & 3;
  const int m0 = blockIdx.y * 128, n0 = blockIdx.x * BN;
  const u16* Abase = P + ((size_t)z << 20);
  const u16* Bbase = Vtb + ((size_t)z << 18);
  const int rl = l >> 3, gsrc8 = ((l & 7) ^ (rl & 7)) * 8;
  const f32x4 fzero = {0.f, 0.f, 0.f, 0.f};
  f32x4 acc[4][NJ];
#pragma unroll
  for (int i = 0; i < 4; i++)
#pragma unroll
    for (int j = 0; j < NJ; j++) acc[i][j] = fzero;

  for (int kt = 0; kt < K; kt += 64) {
    __syncthreads();
#pragma unroll
    for (int c = 0; c < 4; c++) {
      int rb = c * 32 + w * 8;
      async_copy16(&As[rb * 64], Abase + (size_t)(m0 + rb + rl) * K + kt + gsrc8);
    }
#pragma unroll
    for (int c = 0; c < BN / 32; c++) {
      int rb = c * 32 + w * 8;
      async_copy16(&Bs[rb * 64], Bbase + (size_t)(n0 + rb + rl) * K + kt + gsrc8);
    }
    __syncthreads();
#pragma unroll
    for (int kk = 0; kk < 2; kk++) {
      short8 af[4], bf[NJ];
      const int gph = ((kk * 4 + lg) ^ (lm & 7)) * 8;
#pragma unroll
      for (int i = 0; i < 4; i++)
        af[i] = *(const short8*)&As[(wm * 64 + i * 16 + lm) * 64 + gph];
#pragma unroll
      for (int j = 0; j < NJ; j++)
        bf[j] = *(const short8*)&Bs[(wn * (BN / 2) + j * 16 + lm) * 64 + gph];
#pragma unroll
      for (int i = 0; i < 4; i++)
#pragma unroll
        for (int j = 0; j < NJ; j++) acc[i][j] = MFMA16(af[i], bf[j], acc[i][j]);
    }
  }
#pragma unroll
  for (int i = 0; i < 4; i++) {
    int row0 = m0 + wm * 64 + i * 16 + lg * 4;
    float invl[4];
#pragma unroll
    for (int r = 0; r < 4; r++) invl[r] = 1.f / lrow[(z << 10) + row0 + r];
#pragma unroll
    for (int j = 0; j < NJ; j++) {
      int col = n0 + wn * (BN / 2) + j * 16 + lm;
#pragma unroll
      for (int r = 0; r < 4; r++)
        outp[(size_t)((b << 10) + row0 + r) * 1024 + h * 256 + col] =
            f2bf(acc[i][j][r] * invl[r]);
    }
  }
}

// ---------------------------------------------------------------------------
extern "C" void kernel_launch(void* const* d_in, const int* in_sizes, int n_in,
                              void* d_out, int out_size, void* d_ws, size_t ws_size,
                              hipStream_t stream) {
  (void)in_sizes; (void)n_in; (void)out_size; (void)ws_size;
  const float* X      = (const float*)d_in[0];
  const float* cons   = (const float*)d_in[1];
  const float* Wq     = (const float*)d_in[2];  const float* bq     = (const float*)d_in[3];
  const float* Wk     = (const float*)d_in[4];  const float* bk     = (const float*)d_in[5];
  const float* Wv     = (const float*)d_in[6];  const float* bv     = (const float*)d_in[7];
  const float* cgW    = (const float*)d_in[8];  const float* cgb    = (const float*)d_in[9];
  const float* amW    = (const float*)d_in[10]; const float* amb    = (const float*)d_in[11];
  const float* caWin  = (const float*)d_in[12]; const float* cabin  = (const float*)d_in[13];
  const float* caWout = (const float*)d_in[14]; const float* cabout = (const float*)d_in[15];
  const float* mcWin  = (const float*)d_in[16]; const float* mcbin  = (const float*)d_in[17];
  const float* mcWout = (const float*)d_in[18]; const float* mcbout = (const float*)d_in[19];
  const float* Wo     = (const float*)d_in[20]; const float* bo     = (const float*)d_in[21];

  char* ws = (char*)d_ws;
  size_t off = 0;
  auto alloc = [&](size_t bytes) -> void* {
    void* p = ws + off; off += (bytes + 255) & ~(size_t)255; return p;
  };
  u16*    Xbf     = (u16*)alloc((size_t)4096 * 1024 * 2);
  u16*    BtBig   = (u16*)alloc((size_t)6144 * 1024 * 2);        // caWin^T | Wqkv^T
  u16*    mcWinT  = (u16*)alloc((size_t)3072 * 1024 * 2);
  u16*    caWoutT = (u16*)alloc((size_t)1024 * 1024 * 2);
  u16*    mcWoutT = (u16*)alloc((size_t)1024 * 1024 * 2);
  u16*    WoT     = (u16*)alloc((size_t)1024 * 1024 * 2);
  float*  biasBig = (float*)alloc(6144 * 4);
  float*  modb    = (float*)alloc((size_t)64 * 1024 * 4);
  u16*    caQK    = (u16*)alloc((size_t)4096 * 2048 * 2);        // also mcQK
  u16*    qkvm    = (u16*)alloc((size_t)4096 * 3072 * 2);
  u16*    actx    = (u16*)alloc((size_t)4096 * 1024 * 2);
  u16*    ctxm    = (u16*)alloc((size_t)4096 * 1024 * 2);
  u16*    ctx1    = (u16*)alloc((size_t)4096 * 1024 * 2);
  u16*    Pbuf    = (u16*)alloc((size_t)16 * 1024 * 1024 * 2);   // 32 MB
  u16*    Vtb     = (u16*)alloc((size_t)16 * 256 * 1024 * 2);    // 8 MB
  float*  lbuf    = (float*)alloc((size_t)2 * 16384 * 4);        // l_ca | l_mc
  float*  l_ca    = lbuf;
  float*  l_mc    = lbuf + 16384;
  u16*    mcQK    = caQK;  // alias: caQK dead after fused qk
  u16*    mctx    = ctxm;  // alias: ctxm dead after blend1
  u16*    ctx2    = actx;  // alias: actx dead after blend1

  const float SC2 = 1.4426950408889634f / 16.f;   // log2(e)/16

  // ---- prep (2 launches)
  castmod_kernel<<<4096, 256, 0, stream>>>(X, Xbf, cgW, cgb, cons, amW, amb, modb);
  {
    PrepArgs pa;
    for (int s = 0; s < 3; s++) {
      pa.src[s] = caWin + s * 1024; pa.dst[s] = BtBig + (size_t)s * 1024 * 1024;
      pa.sstride[s] = 3072;
    }
    pa.src[3] = Wq; pa.dst[3] = BtBig + (size_t)3072 * 1024; pa.sstride[3] = 1024;
    pa.src[4] = Wk; pa.dst[4] = BtBig + (size_t)4096 * 1024; pa.sstride[4] = 1024;
    pa.src[5] = Wv; pa.dst[5] = BtBig + (size_t)5120 * 1024; pa.sstride[5] = 1024;
    for (int s = 0; s < 3; s++) {
      pa.src[6 + s] = mcWin + s * 1024; pa.dst[6 + s] = mcWinT + (size_t)s * 1024 * 1024;
      pa.sstride[6 + s] = 3072;
    }
    pa.src[9]  = caWout; pa.dst[9]  = caWoutT; pa.sstride[9]  = 1024;
    pa.src[10] = mcWout; pa.dst[10] = mcWoutT; pa.sstride[10] = 1024;
    pa.src[11] = Wo;     pa.dst[11] = WoT;     pa.sstride[11] = 1024;
    pa.cabin = cabin; pa.bq = bq; pa.bk = bk; pa.bv = bv;
    pa.biasBig = biasBig; pa.lbuf = lbuf;
    prep_weights<<<dim3(32, 32, 13), 256, 0, stream>>>(pa);
  }

  // ---- mega in-proj: causal QK + causal V^T + main QKV in one GEMM
  gemm_in3<<<dim3(48, 32), 256, 0, stream>>>(Xbf, BtBig, biasBig, caQK, Vtb, qkvm);
  // ---- fused: main flash attention + causal QK-exp GEMM (independent)
  fused_qk_flash<<<1536, 256, 0, stream>>>(qkvm, modb, ctxm, caQK, Pbuf, l_ca, SC2);
  // ---- causal PV
  gemm_pv<<<dim3(4, 8, 16), 256, 0, stream>>>(Pbuf, Vtb, l_ca, actx);
  // ctx1 = 0.3*ctxm + 0.7*(actx@caWout + cabout)
  gemm_bt<0, 1, 64><<<dim3(16, 32), 256, 0, stream>>>(actx, caWoutT, cabout, ctxm, 0.7f, 0.3f,
                                                      ctx1, 4096, 1024, 1024);
  // ---- meta branch
  gemm_in3<<<dim3(24, 32), 256, 0, stream>>>(ctx1, mcWinT, mcbin, mcQK, Vtb, qkvm /*unused*/);
  gemm_qk_exp<<<dim3(8, 8, 16), 256, 0, stream>>>(mcQK, Pbuf, l_mc, SC2);
  gemm_pv<<<dim3(4, 8, 16), 256, 0, stream>>>(Pbuf, Vtb, l_mc, mctx);
  // ctx2 = 0.85*ctx1 + 0.15*(mctx@mcWout + mcbout)
  gemm_bt<0, 1, 64><<<dim3(16, 32), 256, 0, stream>>>(mctx, mcWoutT, mcbout, ctx1, 0.15f, 0.85f,
                                                      ctx2, 4096, 1024, 1024);
  // out = ctx2@Wo + bo (fp32)
  gemm_bt<1, 0, 64><<<dim3(16, 32), 256, 0, stream>>>(ctx2, WoT, bo, nullptr, 0.f, 0.f,
                                                      d_out, 4096, 1024, 1024);
}